// Round 6
// baseline (113.584 us; speedup 1.0000x reference)
//
#include <hip/hip_runtime.h>
#include <math.h>

// Soft silhouette renderer — wave-split faces (round 6).
// verts: (4, 778, 3) f32   faces: (1538, 3) i32   out: (4, 320, 320) f32
//
// Verified-exact math core (R4, absmax 0.0):
//   area2 = fma(dx1, dy2, -round(dy1*dx2)) — matches the reference
//   evaluator's contraction; degenerate faces (sgn=0 -> 1/8 veil, i1==i2
//   sliver -> sigma=1/2 ridge) reproduced by the generic edge code.
//
// R5 bottleneck (rocprof): VALUBusy 44%, kernel time == worst boundary
// tile's SERIAL j-loop (~1500 faces x ~80 cyc ~= 120k cyc ~= 60 us).
// Fix: 8x8-px tiles, block = 4 waves; all waves share the tile's 64 pixels
// but each handles every 4th compacted face into a private partial acc
// (log1p(-prob) is additive over face subsets — exact). Per-chunk LDS
// reduction of the 4 partials feeds the saturation gate / early exit.
// Critical path /4, cull margin rr 7.5w->3.5w, 6400 blocks for balance.
//
// Error budget vs 2e-2 tolerance (unchanged from R5, measured 3.9e-3):
//   cull skip <= 1538*e^-14 = 1.3e-3; per-pixel gate same bound;
//   early exit <= 2e-9; fast-math ~1 ulp/op.

#define IMG_S 320
#define N_FACES 1538
#define N_VERTS 778
#define TILE 8
#define CHUNK_F 256
#define NWAVE 4
#define INV_SIGMA 100.0f
#define T_CUT 14.0f
#define ACC_CUT -20.0f

__global__ __launch_bounds__(256)
void silhouette_ws(const float* __restrict__ verts,
                   const int* __restrict__ faces,
                   float* __restrict__ out)
{
    __shared__ float4 sE0[CHUNK_F];
    __shared__ float4 sE1[CHUNK_F];
    __shared__ float4 sE2[CHUNK_F];
    __shared__ float sAcc[256];
    __shared__ int sCount;
    __shared__ int sAlive;

    const int t    = threadIdx.x;
    const int wave = t >> 6;
    const int p    = t & 63;          // pixel id within 8x8 tile
    const int b    = blockIdx.z;
    const int lx   = p & 7;
    const int ly   = p >> 3;
    const int gx   = blockIdx.x * TILE + lx;
    const int gy   = blockIdx.y * TILE + ly;

    const float w  = 2.0f / IMG_S;
    const float px = (gx + 0.5f) * w - 1.0f;
    const float py = (gy + 0.5f) * w - 1.0f;
    // center of this tile's 8x8 pixel-center grid, and its half-extent
    const float cx = (blockIdx.x * TILE + 4) * w - 1.0f;
    const float cy = (blockIdx.y * TILE + 4) * w - 1.0f;
    const float rr = 3.5f * w;

    const float* vb = verts + (size_t)b * N_VERTS * 3;

    float acc = 0.0f;   // partial: this wave's subset of faces, my pixel

    const int nchunks = (N_FACES + CHUNK_F - 1) / CHUNK_F;
    for (int c = 0; c < nchunks; ++c) {
        sAcc[t] = acc;                       // partial through chunk c-1
        if (t == 0) { sCount = 0; sAlive = 0; }
        __syncthreads();   // B1 (B3 of prev chunk ordered the j-loop reads)

        // per-pixel total across the 4 wave-partials; stride-64 -> no conflicts
        const float tot = sAcc[p] + sAcc[p + 64] + sAcc[p + 128] + sAcc[p + 192];
        const bool alive = (tot >= ACC_CUT);
        if (alive) sAlive = 1;               // benign same-value race

        const int fc = c * CHUNK_F + t;
        if (fc < N_FACES) {
            const int i0 = faces[fc * 3 + 0];
            const int i1 = faces[fc * 3 + 1];
            const int i2 = faces[fc * 3 + 2];
            const float x0 = vb[i0 * 3 + 0], y0 = -vb[i0 * 3 + 1];
            const float x1 = vb[i1 * 3 + 0], y1 = -vb[i1 * 3 + 1];
            const float x2 = vb[i2 * 3 + 0], y2 = -vb[i2 * 3 + 1];

            // VERIFIED-EXACT (R4): fma-contracted area2, matching the
            // reference. Do not "fix" to separately-rounded form.
            const float dx1 = x1 - x0, dy1 = y1 - y0;
            const float dx2 = x2 - x0, dy2 = y2 - y0;
            const float area2 = __builtin_fmaf(dx1, dy2, -__fmul_rn(dy1, dx2));
            const float sgn = (area2 > 0.0f) ? 1.0f : ((area2 < 0.0f) ? -1.0f : 0.0f);

            float4 e0, e1, e2;
            float mmin;
            {   // edge v0 -> v1
                const float ex = x1 - x0, ey = y1 - y0;
                const float s = sgn * INV_SIGMA / (sqrtf(ex * ex + ey * ey) + 1e-8f);
                const float A = -s * ey, B = s * ex, C = s * (ey * x0 - ex * y0);
                e0 = make_float4(A, B, C, 0.0f);
                mmin = fmaf(A, cx, fmaf(B, cy, C)) + rr * (fabsf(A) + fabsf(B));
            }
            {   // edge v1 -> v2
                const float ex = x2 - x1, ey = y2 - y1;
                const float s = sgn * INV_SIGMA / (sqrtf(ex * ex + ey * ey) + 1e-8f);
                const float A = -s * ey, B = s * ex, C = s * (ey * x1 - ex * y1);
                e1 = make_float4(A, B, C, 0.0f);
                mmin = fminf(mmin, fmaf(A, cx, fmaf(B, cy, C)) + rr * (fabsf(A) + fabsf(B)));
            }
            {   // edge v2 -> v0
                const float ex = x0 - x2, ey = y0 - y2;
                const float s = sgn * INV_SIGMA / (sqrtf(ex * ex + ey * ey) + 1e-8f);
                const float A = -s * ey, B = s * ex, C = s * (ey * x2 - ex * y2);
                e2 = make_float4(A, B, C, 0.0f);
                mmin = fminf(mmin, fmaf(A, cx, fmaf(B, cy, C)) + rr * (fabsf(A) + fabsf(B)));
            }
            if (mmin > -T_CUT) {
                const int slot = atomicAdd(&sCount, 1);
                sE0[slot] = e0;
                sE1[slot] = e1;
                sE2[slot] = e2;
            }
        }
        __syncthreads();   // B2: compaction + alive flag final

        if (sAlive == 0) break;   // uniform: every pixel saturated

        const int n = sCount;
        for (int j = wave; j < n; j += NWAVE) {
            const float4 e0 = sE0[j];   // wave-broadcast reads
            const float4 e1 = sE1[j];
            const float4 e2 = sE2[j];
            const float xa = fmaf(e0.x, px, fmaf(e0.y, py, e0.z));
            const float xb = fmaf(e1.x, px, fmaf(e1.y, py, e1.z));
            const float xc = fmaf(e2.x, px, fmaf(e2.y, py, e2.z));
            const float m = fminf(xa, fminf(xb, xc));
            if (m > -T_CUT && alive) {
                const float pa = __builtin_amdgcn_rcpf(1.0f + __expf(-xa));
                const float pb = __builtin_amdgcn_rcpf(1.0f + __expf(-xb));
                const float pc = __builtin_amdgcn_rcpf(1.0f + __expf(-xc));
                float prob = pa * pb * pc;
                prob = fminf(prob, 1.0f - 1e-6f);
                acc += __logf(1.0f - prob);
            }
        }

        __syncthreads();   // B3: j-loop reads done before next chunk's writes
    }

    // final reduction of the 4 wave-partials (loop exit is uniform: either
    // all waves passed B3, or all broke right after B2)
    sAcc[t] = acc;
    __syncthreads();
    if (t < 64) {
        const float tot = sAcc[p] + sAcc[p + 64] + sAcc[p + 128] + sAcc[p + 192];
        out[(size_t)b * (IMG_S * IMG_S) + (size_t)gy * IMG_S + gx] = 1.0f - __expf(tot);
    }
}

extern "C" void kernel_launch(void* const* d_in, const int* in_sizes, int n_in,
                              void* d_out, int out_size, void* d_ws, size_t ws_size,
                              hipStream_t stream) {
    const float* verts = (const float*)d_in[0];
    const int* faces = (const int*)d_in[1];
    float* out = (float*)d_out;

    dim3 grid(IMG_S / TILE, IMG_S / TILE, 4);
    dim3 block(256);
    silhouette_ws<<<grid, block, 0, stream>>>(verts, faces, out);
}

// Round 7
// 99.642 us; speedup vs baseline: 1.1399x; 1.1399x over previous
//
#include <hip/hip_runtime.h>
#include <math.h>

// Soft silhouette renderer — prep + wave-split render (round 7).
// verts: (4, 778, 3) f32   faces: (1538, 3) i32   out: (4, 320, 320) f32
//
// Verified-exact math core (R4, absmax 0.0):
//   area2 = fma(dx1, dy2, -round(dy1*dx2)) — matches the reference
//   evaluator's contraction; degenerate faces (sgn=0 -> 1/8 veil, i1==i2
//   sliver -> sigma=1/2 ridge) fall out of the generic edge code.
//
// R6 post-mortem: wave-split regressed (60->69 us) because 6400 blocks each
// re-ran the ~100-VALU/face setup for all 1538 faces (9.8M setups) and
// exterior tiles can't early-exit. VALUBusy 82% was redundant setup math.
// Fix: PREP KERNEL computes the 3 affine edge float4s per (batch, face)
// ONCE (6152 setups) into d_ws; render staging = 3 coalesced float4 loads
// + ~20 VALU cull. Render keeps 8x8 tiles, 4-wave face split (j-loop
// critical path /4), LDS compaction, saturation gate, early exit.
//
// Error budget vs 2e-2 tolerance (measured 3.9e-3 at R5/R6, math identical):
//   cull skip <= 1538*e^-14 = 1.3e-3; per-pixel gate same; early exit 2e-9.

#define IMG_S 320
#define N_FACES 1538
#define N_VERTS 778
#define N_BATCH 4
#define FP 1600            // padded face stride in ws
#define TILE 8
#define CHUNK_F 256
#define NWAVE 4
#define INV_SIGMA 100.0f
#define T_CUT 14.0f
#define ACC_CUT -20.0f

__global__ __launch_bounds__(256)
void prep_faces(const float* __restrict__ verts,
                const int* __restrict__ faces,
                float4* __restrict__ gE0,
                float4* __restrict__ gE1,
                float4* __restrict__ gE2)
{
    const int f = blockIdx.x * 256 + threadIdx.x;
    const int b = blockIdx.z;
    if (f >= N_FACES) return;

    const float* vb = verts + (size_t)b * N_VERTS * 3;
    const int i0 = faces[f * 3 + 0];
    const int i1 = faces[f * 3 + 1];
    const int i2 = faces[f * 3 + 2];
    const float x0 = vb[i0 * 3 + 0], y0 = -vb[i0 * 3 + 1];
    const float x1 = vb[i1 * 3 + 0], y1 = -vb[i1 * 3 + 1];
    const float x2 = vb[i2 * 3 + 0], y2 = -vb[i2 * 3 + 1];

    // VERIFIED-EXACT (R4): fma-contracted area2 — do not change.
    const float dx1 = x1 - x0, dy1 = y1 - y0;
    const float dx2 = x2 - x0, dy2 = y2 - y0;
    const float area2 = __builtin_fmaf(dx1, dy2, -__fmul_rn(dy1, dx2));
    const float sgn = (area2 > 0.0f) ? 1.0f : ((area2 < 0.0f) ? -1.0f : 0.0f);

    const size_t o = (size_t)b * FP + f;
    {   // edge v0 -> v1
        const float ex = x1 - x0, ey = y1 - y0;
        const float s = sgn * INV_SIGMA / (sqrtf(ex * ex + ey * ey) + 1e-8f);
        gE0[o] = make_float4(-s * ey, s * ex, s * (ey * x0 - ex * y0), 0.0f);
    }
    {   // edge v1 -> v2
        const float ex = x2 - x1, ey = y2 - y1;
        const float s = sgn * INV_SIGMA / (sqrtf(ex * ex + ey * ey) + 1e-8f);
        gE1[o] = make_float4(-s * ey, s * ex, s * (ey * x1 - ex * y1), 0.0f);
    }
    {   // edge v2 -> v0
        const float ex = x0 - x2, ey = y0 - y2;
        const float s = sgn * INV_SIGMA / (sqrtf(ex * ex + ey * ey) + 1e-8f);
        gE2[o] = make_float4(-s * ey, s * ex, s * (ey * x2 - ex * y2), 0.0f);
    }
}

__global__ __launch_bounds__(256)
void silhouette_ws(const float4* __restrict__ gE0,
                   const float4* __restrict__ gE1,
                   const float4* __restrict__ gE2,
                   float* __restrict__ out)
{
    __shared__ float4 sE0[CHUNK_F];
    __shared__ float4 sE1[CHUNK_F];
    __shared__ float4 sE2[CHUNK_F];
    __shared__ float sAcc[256];
    __shared__ int sCount;
    __shared__ int sAlive;

    const int t    = threadIdx.x;
    const int wave = t >> 6;
    const int p    = t & 63;          // pixel id within 8x8 tile
    const int b    = blockIdx.z;
    const int lx   = p & 7;
    const int ly   = p >> 3;
    const int gx   = blockIdx.x * TILE + lx;
    const int gy   = blockIdx.y * TILE + ly;

    const float w  = 2.0f / IMG_S;
    const float px = (gx + 0.5f) * w - 1.0f;
    const float py = (gy + 0.5f) * w - 1.0f;
    const float cx = (blockIdx.x * TILE + 4) * w - 1.0f;
    const float cy = (blockIdx.y * TILE + 4) * w - 1.0f;
    const float rr = 3.5f * w;

    float acc = 0.0f;   // partial: this wave's face subset, my pixel

    const int nchunks = (N_FACES + CHUNK_F - 1) / CHUNK_F;
    for (int c = 0; c < nchunks; ++c) {
        sAcc[t] = acc;
        if (t == 0) { sCount = 0; sAlive = 0; }
        __syncthreads();   // B1

        const float tot = sAcc[p] + sAcc[p + 64] + sAcc[p + 128] + sAcc[p + 192];
        const bool alive = (tot >= ACC_CUT);
        if (alive) sAlive = 1;               // benign same-value race

        const int fc = c * CHUNK_F + t;
        if (fc < N_FACES) {
            const size_t o = (size_t)b * FP + fc;
            const float4 e0 = gE0[o];        // coalesced 16B/lane
            const float4 e1 = gE1[o];
            const float4 e2 = gE2[o];
            float mmin =       fmaf(e0.x, cx, fmaf(e0.y, cy, e0.z)) + rr * (fabsf(e0.x) + fabsf(e0.y));
            mmin = fminf(mmin, fmaf(e1.x, cx, fmaf(e1.y, cy, e1.z)) + rr * (fabsf(e1.x) + fabsf(e1.y)));
            mmin = fminf(mmin, fmaf(e2.x, cx, fmaf(e2.y, cy, e2.z)) + rr * (fabsf(e2.x) + fabsf(e2.y)));
            if (mmin > -T_CUT) {
                const int slot = atomicAdd(&sCount, 1);
                sE0[slot] = e0;
                sE1[slot] = e1;
                sE2[slot] = e2;
            }
        }
        __syncthreads();   // B2: compaction + alive flag final

        if (sAlive == 0) break;   // uniform: every pixel saturated

        const int n = sCount;
        for (int j = wave; j < n; j += NWAVE) {
            const float4 e0 = sE0[j];   // wave-broadcast reads
            const float4 e1 = sE1[j];
            const float4 e2 = sE2[j];
            const float xa = fmaf(e0.x, px, fmaf(e0.y, py, e0.z));
            const float xb = fmaf(e1.x, px, fmaf(e1.y, py, e1.z));
            const float xc = fmaf(e2.x, px, fmaf(e2.y, py, e2.z));
            const float m = fminf(xa, fminf(xb, xc));
            if (m > -T_CUT && alive) {
                const float pa = __builtin_amdgcn_rcpf(1.0f + __expf(-xa));
                const float pb = __builtin_amdgcn_rcpf(1.0f + __expf(-xb));
                const float pc = __builtin_amdgcn_rcpf(1.0f + __expf(-xc));
                float prob = pa * pb * pc;
                prob = fminf(prob, 1.0f - 1e-6f);
                acc += __logf(1.0f - prob);
            }
        }

        __syncthreads();   // B3: j-loop reads done before next chunk's writes
    }

    sAcc[t] = acc;
    __syncthreads();
    if (t < 64) {
        const float tot = sAcc[p] + sAcc[p + 64] + sAcc[p + 128] + sAcc[p + 192];
        out[(size_t)b * (IMG_S * IMG_S) + (size_t)gy * IMG_S + gx] = 1.0f - __expf(tot);
    }
}

extern "C" void kernel_launch(void* const* d_in, const int* in_sizes, int n_in,
                              void* d_out, int out_size, void* d_ws, size_t ws_size,
                              hipStream_t stream) {
    const float* verts = (const float*)d_in[0];
    const int* faces = (const int*)d_in[1];
    float* out = (float*)d_out;

    // ws layout: 3 arrays of float4[N_BATCH * FP]  (3 * 4*1600*16B = 307 KB)
    float4* gE0 = (float4*)d_ws;
    float4* gE1 = gE0 + (size_t)N_BATCH * FP;
    float4* gE2 = gE1 + (size_t)N_BATCH * FP;

    dim3 pgrid((N_FACES + 255) / 256, 1, N_BATCH);
    prep_faces<<<pgrid, 256, 0, stream>>>(verts, faces, gE0, gE1, gE2);

    dim3 grid(IMG_S / TILE, IMG_S / TILE, N_BATCH);
    silhouette_ws<<<grid, 256, 0, stream>>>(gE0, gE1, gE2, out);
}

// Round 8
// 95.274 us; speedup vs baseline: 1.1922x; 1.0458x over previous
//
#include <hip/hip_runtime.h>
#include <math.h>

// Soft silhouette renderer — prep + wave-split render, product domain (R8).
// verts: (4, 778, 3) f32   faces: (1538, 3) i32   out: (4, 320, 320) f32
//
// Verified-exact math core (R4, absmax 0.0):
//   area2 = fma(dx1, dy2, -round(dy1*dx2)) — matches the reference
//   evaluator's contraction; degenerate faces (sgn=0 -> 1/8 veil, i1==i2
//   sliver -> sigma=1/2 ridge) fall out of the generic edge code.
//
// R7 post-mortem: aggregate-VALU-bound; j-loop body = 7 transcendental-class
// ops x 8 cyc (quarter-rate wave64). This round:
//  * PRODUCT DOMAIN: out = 1 - prod(1-prob) == 1 - exp(sum log1p(-prob)).
//    Kills __logf per face + final __expf. Underflow->0 -> out=1 (ref within
//    2e-9 of 1 there). Alive gate: acc_prod > e^-20.
//  * DEEP-INTERIOR SHORTCUT: m > +14 -> true factor in [1e-6, 2.5e-6]
//    (ref clips prob at 1-1e-6); use 1e-6 -> <=1.5e-6 abs error, ZERO
//    transcendentals for covering faces.
//  * in-band path: 3 exp + 1 rcp (was 3 exp + 3 rcp + 1 log).
//
// Error budget vs 2e-2 tolerance (measured 3.9e-3 at R5-R7):
//   cull skip <= 1538*e^-14 = 1.3e-3; pixel gate same; early exit 2e-9;
//   interior shortcut 1.5e-6; product rounding ~1e-4.

#define IMG_S 320
#define N_FACES 1538
#define N_VERTS 778
#define N_BATCH 4
#define FP 1600            // padded face stride in ws
#define TILE 8
#define CHUNK_F 256
#define NWAVE 4
#define INV_SIGMA 100.0f
#define T_CUT 14.0f
#define ACC_CUT_P 2.0611536e-9f   // e^-20, product-domain saturation

__global__ __launch_bounds__(256)
void prep_faces(const float* __restrict__ verts,
                const int* __restrict__ faces,
                float4* __restrict__ gE0,
                float4* __restrict__ gE1,
                float4* __restrict__ gE2)
{
    const int f = blockIdx.x * 256 + threadIdx.x;
    const int b = blockIdx.z;
    if (f >= N_FACES) return;

    const float* vb = verts + (size_t)b * N_VERTS * 3;
    const int i0 = faces[f * 3 + 0];
    const int i1 = faces[f * 3 + 1];
    const int i2 = faces[f * 3 + 2];
    const float x0 = vb[i0 * 3 + 0], y0 = -vb[i0 * 3 + 1];
    const float x1 = vb[i1 * 3 + 0], y1 = -vb[i1 * 3 + 1];
    const float x2 = vb[i2 * 3 + 0], y2 = -vb[i2 * 3 + 1];

    // VERIFIED-EXACT (R4): fma-contracted area2 — do not change.
    const float dx1 = x1 - x0, dy1 = y1 - y0;
    const float dx2 = x2 - x0, dy2 = y2 - y0;
    const float area2 = __builtin_fmaf(dx1, dy2, -__fmul_rn(dy1, dx2));
    const float sgn = (area2 > 0.0f) ? 1.0f : ((area2 < 0.0f) ? -1.0f : 0.0f);

    const size_t o = (size_t)b * FP + f;
    {   // edge v0 -> v1
        const float ex = x1 - x0, ey = y1 - y0;
        const float s = sgn * INV_SIGMA / (sqrtf(ex * ex + ey * ey) + 1e-8f);
        gE0[o] = make_float4(-s * ey, s * ex, s * (ey * x0 - ex * y0), 0.0f);
    }
    {   // edge v1 -> v2
        const float ex = x2 - x1, ey = y2 - y1;
        const float s = sgn * INV_SIGMA / (sqrtf(ex * ex + ey * ey) + 1e-8f);
        gE1[o] = make_float4(-s * ey, s * ex, s * (ey * x1 - ex * y1), 0.0f);
    }
    {   // edge v2 -> v0
        const float ex = x0 - x2, ey = y0 - y2;
        const float s = sgn * INV_SIGMA / (sqrtf(ex * ex + ey * ey) + 1e-8f);
        gE2[o] = make_float4(-s * ey, s * ex, s * (ey * x2 - ex * y2), 0.0f);
    }
}

__global__ __launch_bounds__(256)
void silhouette_ws(const float4* __restrict__ gE0,
                   const float4* __restrict__ gE1,
                   const float4* __restrict__ gE2,
                   float* __restrict__ out)
{
    __shared__ float4 sE0[CHUNK_F];
    __shared__ float4 sE1[CHUNK_F];
    __shared__ float4 sE2[CHUNK_F];
    __shared__ float sAcc[256];
    __shared__ int sCount;
    __shared__ int sAlive;

    const int t    = threadIdx.x;
    const int wave = t >> 6;
    const int p    = t & 63;          // pixel id within 8x8 tile
    const int b    = blockIdx.z;
    const int lx   = p & 7;
    const int ly   = p >> 3;
    const int gx   = blockIdx.x * TILE + lx;
    const int gy   = blockIdx.y * TILE + ly;

    const float w  = 2.0f / IMG_S;
    const float px = (gx + 0.5f) * w - 1.0f;
    const float py = (gy + 0.5f) * w - 1.0f;
    const float cx = (blockIdx.x * TILE + 4) * w - 1.0f;
    const float cy = (blockIdx.y * TILE + 4) * w - 1.0f;
    const float rr = 3.5f * w;

    float acc = 1.0f;   // PRODUCT of (1-prob) over this wave's face subset

    const int nchunks = (N_FACES + CHUNK_F - 1) / CHUNK_F;
    for (int c = 0; c < nchunks; ++c) {
        sAcc[t] = acc;
        if (t == 0) { sCount = 0; sAlive = 0; }
        __syncthreads();   // B1

        const float tot = sAcc[p] * sAcc[p + 64] * sAcc[p + 128] * sAcc[p + 192];
        const bool alive = (tot > ACC_CUT_P);
        if (alive) sAlive = 1;               // benign same-value race

        const int fc = c * CHUNK_F + t;
        if (fc < N_FACES) {
            const size_t o = (size_t)b * FP + fc;
            const float4 e0 = gE0[o];        // coalesced 16B/lane
            const float4 e1 = gE1[o];
            const float4 e2 = gE2[o];
            float mmin =       fmaf(e0.x, cx, fmaf(e0.y, cy, e0.z)) + rr * (fabsf(e0.x) + fabsf(e0.y));
            mmin = fminf(mmin, fmaf(e1.x, cx, fmaf(e1.y, cy, e1.z)) + rr * (fabsf(e1.x) + fabsf(e1.y)));
            mmin = fminf(mmin, fmaf(e2.x, cx, fmaf(e2.y, cy, e2.z)) + rr * (fabsf(e2.x) + fabsf(e2.y)));
            if (mmin > -T_CUT) {
                const int slot = atomicAdd(&sCount, 1);
                sE0[slot] = e0;
                sE1[slot] = e1;
                sE2[slot] = e2;
            }
        }
        __syncthreads();   // B2: compaction + alive flag final

        if (sAlive == 0) break;   // uniform: every pixel saturated

        const int n = sCount;
        for (int j = wave; j < n; j += NWAVE) {
            const float4 e0 = sE0[j];   // wave-broadcast reads
            const float4 e1 = sE1[j];
            const float4 e2 = sE2[j];
            const float xa = fmaf(e0.x, px, fmaf(e0.y, py, e0.z));
            const float xb = fmaf(e1.x, px, fmaf(e1.y, py, e1.z));
            const float xc = fmaf(e2.x, px, fmaf(e2.y, py, e2.z));
            const float m = fminf(xa, fminf(xb, xc));
            if (m > -T_CUT && alive) {
                if (m > T_CUT) {
                    // all three sigmoids ~1; ref clips prob to <= 1-1e-6, so
                    // true factor in [1e-6, 2.5e-6] -> <=1.5e-6 abs error
                    acc *= 1e-6f;
                } else {
                    const float da = 1.0f + __expf(-xa);
                    const float db = 1.0f + __expf(-xb);
                    const float dc = 1.0f + __expf(-xc);
                    const float prob = __builtin_amdgcn_rcpf(da * db * dc);
                    acc *= fmaxf(1.0f - prob, 1e-6f);
                }
            }
        }

        __syncthreads();   // B3: j-loop reads done before next chunk's writes
    }

    sAcc[t] = acc;
    __syncthreads();
    if (t < 64) {
        const float tot = sAcc[p] * sAcc[p + 64] * sAcc[p + 128] * sAcc[p + 192];
        out[(size_t)b * (IMG_S * IMG_S) + (size_t)gy * IMG_S + gx] = 1.0f - tot;
    }
}

extern "C" void kernel_launch(void* const* d_in, const int* in_sizes, int n_in,
                              void* d_out, int out_size, void* d_ws, size_t ws_size,
                              hipStream_t stream) {
    const float* verts = (const float*)d_in[0];
    const int* faces = (const int*)d_in[1];
    float* out = (float*)d_out;

    // ws layout: 3 arrays of float4[N_BATCH * FP]  (3 * 4*1600*16B = 307 KB)
    float4* gE0 = (float4*)d_ws;
    float4* gE1 = gE0 + (size_t)N_BATCH * FP;
    float4* gE2 = gE1 + (size_t)N_BATCH * FP;

    dim3 pgrid((N_FACES + 255) / 256, 1, N_BATCH);
    prep_faces<<<pgrid, 256, 0, stream>>>(verts, faces, gE0, gE1, gE2);

    dim3 grid(IMG_S / TILE, IMG_S / TILE, N_BATCH);
    silhouette_ws<<<grid, 256, 0, stream>>>(gE0, gE1, gE2, out);
}

// Round 9
// 95.113 us; speedup vs baseline: 1.1942x; 1.0017x over previous
//
#include <hip/hip_runtime.h>
#include <math.h>

// Soft silhouette renderer — prep + wave-split render, dynamic gates (R9).
// verts: (4, 778, 3) f32   faces: (1538, 3) i32   out: (4, 320, 320) f32
//
// Verified-exact math core (R4, absmax 0.0):
//   area2 = fma(dx1, dy2, -round(dy1*dx2)) — matches the reference
//   evaluator's contraction; degenerate faces (sgn=0 -> 1/8 veil, i1==i2
//   sliver -> sigma=1/2 ridge) fall out of the generic edge code.
//
// R8 post-mortem: VALUBusy fell to 56% — j-loop is part latency-bound and
// part wasted on saturated pixels (alive gate frozen per chunk; ~115x face
// coverage saturates interior pixels after 2 covering faces). This round:
//  * PER-LANE DYNAMIC LIVE GATE: factors are <= 1, so a wave-partial
//    acc < e^-20 implies the 4-wave total is saturated — safe to kill the
//    lane mid-chunk. Wave breaks out of the j-loop when __ballot(live)==0.
//  * SINGLE-EDGE FAST PATH: if median(xa,xb,xc) > 14, the other two
//    sigmoids are within 1.7e-6 of 1 -> factor = rcp(1 + e^m)  (1 exp
//    instead of 3; same 1e-6 floor as the reference clip).
//  * keeps R8: product domain, covering shortcut (m>14 -> *=1e-6),
//    tile cull + LDS compaction, chunk-level early exit on true total.
//
// Error budget vs 2e-2 tolerance (measured 3.9e-3 at R5-R8):
//   cull skip <= 1538*e^-14 = 1.3e-3; pixel gate same; early exit 2e-9;
//   covering shortcut 1.5e-6; single-edge path 1.7e-6; product rounding ~1e-4.

#define IMG_S 320
#define N_FACES 1538
#define N_VERTS 778
#define N_BATCH 4
#define FP 1600            // padded face stride in ws
#define TILE 8
#define CHUNK_F 256
#define NWAVE 4
#define INV_SIGMA 100.0f
#define T_CUT 14.0f
#define ACC_CUT_P 2.0611536e-9f   // e^-20, product-domain saturation

__global__ __launch_bounds__(256)
void prep_faces(const float* __restrict__ verts,
                const int* __restrict__ faces,
                float4* __restrict__ gE0,
                float4* __restrict__ gE1,
                float4* __restrict__ gE2)
{
    const int f = blockIdx.x * 256 + threadIdx.x;
    const int b = blockIdx.z;
    if (f >= N_FACES) return;

    const float* vb = verts + (size_t)b * N_VERTS * 3;
    const int i0 = faces[f * 3 + 0];
    const int i1 = faces[f * 3 + 1];
    const int i2 = faces[f * 3 + 2];
    const float x0 = vb[i0 * 3 + 0], y0 = -vb[i0 * 3 + 1];
    const float x1 = vb[i1 * 3 + 0], y1 = -vb[i1 * 3 + 1];
    const float x2 = vb[i2 * 3 + 0], y2 = -vb[i2 * 3 + 1];

    // VERIFIED-EXACT (R4): fma-contracted area2 — do not change.
    const float dx1 = x1 - x0, dy1 = y1 - y0;
    const float dx2 = x2 - x0, dy2 = y2 - y0;
    const float area2 = __builtin_fmaf(dx1, dy2, -__fmul_rn(dy1, dx2));
    const float sgn = (area2 > 0.0f) ? 1.0f : ((area2 < 0.0f) ? -1.0f : 0.0f);

    const size_t o = (size_t)b * FP + f;
    {   // edge v0 -> v1
        const float ex = x1 - x0, ey = y1 - y0;
        const float s = sgn * INV_SIGMA / (sqrtf(ex * ex + ey * ey) + 1e-8f);
        gE0[o] = make_float4(-s * ey, s * ex, s * (ey * x0 - ex * y0), 0.0f);
    }
    {   // edge v1 -> v2
        const float ex = x2 - x1, ey = y2 - y1;
        const float s = sgn * INV_SIGMA / (sqrtf(ex * ex + ey * ey) + 1e-8f);
        gE1[o] = make_float4(-s * ey, s * ex, s * (ey * x1 - ex * y1), 0.0f);
    }
    {   // edge v2 -> v0
        const float ex = x0 - x2, ey = y0 - y2;
        const float s = sgn * INV_SIGMA / (sqrtf(ex * ex + ey * ey) + 1e-8f);
        gE2[o] = make_float4(-s * ey, s * ex, s * (ey * x2 - ex * y2), 0.0f);
    }
}

__global__ __launch_bounds__(256)
void silhouette_ws(const float4* __restrict__ gE0,
                   const float4* __restrict__ gE1,
                   const float4* __restrict__ gE2,
                   float* __restrict__ out)
{
    __shared__ float4 sE0[CHUNK_F];
    __shared__ float4 sE1[CHUNK_F];
    __shared__ float4 sE2[CHUNK_F];
    __shared__ float sAcc[256];
    __shared__ int sCount;
    __shared__ int sAlive;

    const int t    = threadIdx.x;
    const int wave = t >> 6;
    const int p    = t & 63;          // pixel id within 8x8 tile
    const int b    = blockIdx.z;
    const int lx   = p & 7;
    const int ly   = p >> 3;
    const int gx   = blockIdx.x * TILE + lx;
    const int gy   = blockIdx.y * TILE + ly;

    const float w  = 2.0f / IMG_S;
    const float px = (gx + 0.5f) * w - 1.0f;
    const float py = (gy + 0.5f) * w - 1.0f;
    const float cx = (blockIdx.x * TILE + 4) * w - 1.0f;
    const float cy = (blockIdx.y * TILE + 4) * w - 1.0f;
    const float rr = 3.5f * w;

    float acc = 1.0f;   // PRODUCT of (1-prob) over this wave's face subset

    const int nchunks = (N_FACES + CHUNK_F - 1) / CHUNK_F;
    for (int c = 0; c < nchunks; ++c) {
        sAcc[t] = acc;
        if (t == 0) { sCount = 0; sAlive = 0; }
        __syncthreads();   // B1

        const float tot = sAcc[p] * sAcc[p + 64] * sAcc[p + 128] * sAcc[p + 192];
        const bool alive = (tot > ACC_CUT_P);
        if (alive) sAlive = 1;               // benign same-value race

        const int fc = c * CHUNK_F + t;
        if (fc < N_FACES) {
            const size_t o = (size_t)b * FP + fc;
            const float4 e0 = gE0[o];        // coalesced 16B/lane
            const float4 e1 = gE1[o];
            const float4 e2 = gE2[o];
            float mmin =       fmaf(e0.x, cx, fmaf(e0.y, cy, e0.z)) + rr * (fabsf(e0.x) + fabsf(e0.y));
            mmin = fminf(mmin, fmaf(e1.x, cx, fmaf(e1.y, cy, e1.z)) + rr * (fabsf(e1.x) + fabsf(e1.y)));
            mmin = fminf(mmin, fmaf(e2.x, cx, fmaf(e2.y, cy, e2.z)) + rr * (fabsf(e2.x) + fabsf(e2.y)));
            if (mmin > -T_CUT) {
                const int slot = atomicAdd(&sCount, 1);
                sE0[slot] = e0;
                sE1[slot] = e1;
                sE2[slot] = e2;
            }
        }
        __syncthreads();   // B2: compaction + alive flag final

        if (sAlive == 0) break;   // uniform: every pixel saturated

        const int n = sCount;
        // per-lane dynamic gate: factors <= 1, so partial < cut => total < cut
        bool live = alive && (acc > ACC_CUT_P);
        for (int j = wave; j < n; j += NWAVE) {
            if (__ballot(live) == 0ull) break;   // whole wave saturated
            const float4 e0 = sE0[j];   // wave-broadcast reads
            const float4 e1 = sE1[j];
            const float4 e2 = sE2[j];
            const float xa = fmaf(e0.x, px, fmaf(e0.y, py, e0.z));
            const float xb = fmaf(e1.x, px, fmaf(e1.y, py, e1.z));
            const float xc = fmaf(e2.x, px, fmaf(e2.y, py, e2.z));
            const float m = fminf(xa, fminf(xb, xc));
            if (live && m > -T_CUT) {
                if (m > T_CUT) {
                    // covering face: ref clips prob to <= 1-1e-6; true factor
                    // in [1e-6, 2.5e-6] -> use 1e-6, <=1.5e-6 abs error
                    acc *= 1e-6f;
                } else {
                    const float mid = fmaxf(fminf(fmaxf(xa, xb), xc),
                                            fminf(xa, xb));   // median
                    float f;
                    if (mid > T_CUT) {
                        // only one edge in band: factor = sigma(-m)
                        f = __builtin_amdgcn_rcpf(1.0f + __expf(m));
                    } else {
                        const float da = 1.0f + __expf(-xa);
                        const float db = 1.0f + __expf(-xb);
                        const float dc = 1.0f + __expf(-xc);
                        f = 1.0f - __builtin_amdgcn_rcpf(da * db * dc);
                    }
                    acc *= fmaxf(f, 1e-6f);
                }
                live = (acc > ACC_CUT_P);
            }
        }

        __syncthreads();   // B3: j-loop reads done before next chunk's writes
    }

    sAcc[t] = acc;
    __syncthreads();
    if (t < 64) {
        const float tot = sAcc[p] * sAcc[p + 64] * sAcc[p + 128] * sAcc[p + 192];
        out[(size_t)b * (IMG_S * IMG_S) + (size_t)gy * IMG_S + gx] = 1.0f - tot;
    }
}

extern "C" void kernel_launch(void* const* d_in, const int* in_sizes, int n_in,
                              void* d_out, int out_size, void* d_ws, size_t ws_size,
                              hipStream_t stream) {
    const float* verts = (const float*)d_in[0];
    const int* faces = (const int*)d_in[1];
    float* out = (float*)d_out;

    // ws layout: 3 arrays of float4[N_BATCH * FP]  (3 * 4*1600*16B = 307 KB)
    float4* gE0 = (float4*)d_ws;
    float4* gE1 = gE0 + (size_t)N_BATCH * FP;
    float4* gE2 = gE1 + (size_t)N_BATCH * FP;

    dim3 pgrid((N_FACES + 255) / 256, 1, N_BATCH);
    prep_faces<<<pgrid, 256, 0, stream>>>(verts, faces, gE0, gE1, gE2);

    dim3 grid(IMG_S / TILE, IMG_S / TILE, N_BATCH);
    silhouette_ws<<<grid, 256, 0, stream>>>(gE0, gE1, gE2, out);
}

// Round 11
// 92.080 us; speedup vs baseline: 1.2335x; 1.0329x over previous
//
#include <hip/hip_runtime.h>
#include <math.h>

// Soft silhouette renderer — prep + wave-split render, cover-count (R11).
// verts: (4, 778, 3) f32   faces: (1538, 3) i32   out: (4, 320, 320) f32
//
// Verified-exact math core (R4, absmax 0.0):
//   area2 = fma(dx1, dy2, -round(dy1*dx2)) — matches the reference
//   evaluator's contraction; degenerate faces (sgn=0 -> 1/8 veil, i1==i2
//   sliver -> sigma=1/2 ridge) fall out of the generic edge code.
//
// R9 post-mortem: j-loop cost = fixed ~26 cyc x ~440 survivors/tile (huge
// triangles: ~140 covering + ~300 band). Covering faces contribute the
// SAME factor 1e-6 (ref clip) to every pixel of a fully-covered tile.
// This round: count them at cull time (sCover) instead of compacting;
// apply coverF = exp2f(k * log2 1e-6) once per chunk (folded into wave 0's
// partial; in every lane's entry gate via total <= my_partial * coverF).
//  -> covering faces cost ~0; interior tiles see coverF < e^-20 BEFORE the
//     j-loop and skip the band scan entirely. Critical path = exterior
//     near-boundary tiles (~300 band faces).
// (R10 was this exact kernel but used __exp2f, which is not a HIP device
//  function — compile error. exp2f is the device-side spelling.)
// Keeps: product domain, per-pixel m>T shortcut, single-edge fast path,
// per-lane live gate + wave ballot-break, chunk early exit, tile cull +
// LDS compaction of band faces.
//
// Error budget vs 2e-2 tolerance (measured 3.9e-3 at R5-R9):
//   cull skip <= 1538*e^-14 = 1.3e-3; cover factor: identical 1e-6-floor
//   semantics as the per-pixel shortcut (<=1.5e-6/face); underflow->0 ->
//   out=1 exactly (ref within 2e-9); product rounding ~1e-4.

#define IMG_S 320
#define N_FACES 1538
#define N_VERTS 778
#define N_BATCH 4
#define FP 1600            // padded face stride in ws
#define TILE 8
#define CHUNK_F 256
#define NWAVE 4
#define INV_SIGMA 100.0f
#define T_CUT 14.0f
#define ACC_CUT_P 2.0611536e-9f    // e^-20, product-domain saturation
#define LOG2_1EM6 -19.9315686f     // log2(1e-6)

__global__ __launch_bounds__(256)
void prep_faces(const float* __restrict__ verts,
                const int* __restrict__ faces,
                float4* __restrict__ gE0,
                float4* __restrict__ gE1,
                float4* __restrict__ gE2)
{
    const int f = blockIdx.x * 256 + threadIdx.x;
    const int b = blockIdx.z;
    if (f >= N_FACES) return;

    const float* vb = verts + (size_t)b * N_VERTS * 3;
    const int i0 = faces[f * 3 + 0];
    const int i1 = faces[f * 3 + 1];
    const int i2 = faces[f * 3 + 2];
    const float x0 = vb[i0 * 3 + 0], y0 = -vb[i0 * 3 + 1];
    const float x1 = vb[i1 * 3 + 0], y1 = -vb[i1 * 3 + 1];
    const float x2 = vb[i2 * 3 + 0], y2 = -vb[i2 * 3 + 1];

    // VERIFIED-EXACT (R4): fma-contracted area2 — do not change.
    const float dx1 = x1 - x0, dy1 = y1 - y0;
    const float dx2 = x2 - x0, dy2 = y2 - y0;
    const float area2 = __builtin_fmaf(dx1, dy2, -__fmul_rn(dy1, dx2));
    const float sgn = (area2 > 0.0f) ? 1.0f : ((area2 < 0.0f) ? -1.0f : 0.0f);

    const size_t o = (size_t)b * FP + f;
    {   // edge v0 -> v1
        const float ex = x1 - x0, ey = y1 - y0;
        const float s = sgn * INV_SIGMA / (sqrtf(ex * ex + ey * ey) + 1e-8f);
        gE0[o] = make_float4(-s * ey, s * ex, s * (ey * x0 - ex * y0), 0.0f);
    }
    {   // edge v1 -> v2
        const float ex = x2 - x1, ey = y2 - y1;
        const float s = sgn * INV_SIGMA / (sqrtf(ex * ex + ey * ey) + 1e-8f);
        gE1[o] = make_float4(-s * ey, s * ex, s * (ey * x1 - ex * y1), 0.0f);
    }
    {   // edge v2 -> v0
        const float ex = x0 - x2, ey = y0 - y2;
        const float s = sgn * INV_SIGMA / (sqrtf(ex * ex + ey * ey) + 1e-8f);
        gE2[o] = make_float4(-s * ey, s * ex, s * (ey * x2 - ex * y2), 0.0f);
    }
}

__global__ __launch_bounds__(256)
void silhouette_ws(const float4* __restrict__ gE0,
                   const float4* __restrict__ gE1,
                   const float4* __restrict__ gE2,
                   float* __restrict__ out)
{
    __shared__ float4 sE0[CHUNK_F];
    __shared__ float4 sE1[CHUNK_F];
    __shared__ float4 sE2[CHUNK_F];
    __shared__ float sAcc[256];
    __shared__ int sCount;
    __shared__ int sAlive;
    __shared__ int sCover;

    const int t    = threadIdx.x;
    const int wave = t >> 6;
    const int p    = t & 63;          // pixel id within 8x8 tile
    const int b    = blockIdx.z;
    const int lx   = p & 7;
    const int ly   = p >> 3;
    const int gx   = blockIdx.x * TILE + lx;
    const int gy   = blockIdx.y * TILE + ly;

    const float w  = 2.0f / IMG_S;
    const float px = (gx + 0.5f) * w - 1.0f;
    const float py = (gy + 0.5f) * w - 1.0f;
    const float cx = (blockIdx.x * TILE + 4) * w - 1.0f;
    const float cy = (blockIdx.y * TILE + 4) * w - 1.0f;
    const float rr = 3.5f * w;

    float acc = 1.0f;   // PRODUCT of (1-prob) over this wave's face subset
                        // (wave 0's partial also carries the cover factors)

    const int nchunks = (N_FACES + CHUNK_F - 1) / CHUNK_F;
    for (int c = 0; c < nchunks; ++c) {
        sAcc[t] = acc;
        if (t == 0) { sCount = 0; sAlive = 0; sCover = 0; }
        __syncthreads();   // B1

        const float tot = sAcc[p] * sAcc[p + 64] * sAcc[p + 128] * sAcc[p + 192];
        const bool alive = (tot > ACC_CUT_P);
        if (alive) sAlive = 1;               // benign same-value race

        const int fc = c * CHUNK_F + t;
        if (fc < N_FACES) {
            const size_t o = (size_t)b * FP + fc;
            const float4 e0 = gE0[o];        // coalesced 16B/lane
            const float4 e1 = gE1[o];
            const float4 e2 = gE2[o];
            // per-edge affine at tile center +/- half-extent reach
            const float c0 = fmaf(e0.x, cx, fmaf(e0.y, cy, e0.z));
            const float c1 = fmaf(e1.x, cx, fmaf(e1.y, cy, e1.z));
            const float c2 = fmaf(e2.x, cx, fmaf(e2.y, cy, e2.z));
            const float r0 = rr * (fabsf(e0.x) + fabsf(e0.y));
            const float r1 = rr * (fabsf(e1.x) + fabsf(e1.y));
            const float r2 = rr * (fabsf(e2.x) + fabsf(e2.y));
            const float m_hi = fminf(c0 + r0, fminf(c1 + r1, c2 + r2));
            const float m_lo = fminf(c0 - r0, fminf(c1 - r1, c2 - r2));
            if (m_lo > T_CUT) {
                // covers every pixel of the tile: identical factor 1e-6
                atomicAdd(&sCover, 1);
            } else if (m_hi > -T_CUT) {
                const int slot = atomicAdd(&sCount, 1);
                sE0[slot] = e0;
                sE1[slot] = e1;
                sE2[slot] = e2;
            }
        }
        __syncthreads();   // B2: compaction + cover count + alive flag final

        if (sAlive == 0) break;   // uniform: every pixel saturated

        // cover factor for this chunk: applied once (wave 0's partial);
        // every lane's entry gate may use total <= my_partial * coverF
        const float coverF = exp2f((float)sCover * LOG2_1EM6);
        bool live = alive && (acc * coverF > ACC_CUT_P);
        if (wave == 0) acc *= coverF;

        const int n = sCount;
        for (int j = wave; j < n; j += NWAVE) {
            if (__ballot(live) == 0ull) break;   // whole wave saturated
            const float4 e0 = sE0[j];   // wave-broadcast reads
            const float4 e1 = sE1[j];
            const float4 e2 = sE2[j];
            const float xa = fmaf(e0.x, px, fmaf(e0.y, py, e0.z));
            const float xb = fmaf(e1.x, px, fmaf(e1.y, py, e1.z));
            const float xc = fmaf(e2.x, px, fmaf(e2.y, py, e2.z));
            const float m = fminf(xa, fminf(xb, xc));
            if (live && m > -T_CUT) {
                if (m > T_CUT) {
                    // pixel-covering face: ref clips prob at 1-1e-6
                    acc *= 1e-6f;
                } else {
                    const float mid = fmaxf(fminf(fmaxf(xa, xb), xc),
                                            fminf(xa, xb));   // median
                    float f;
                    if (mid > T_CUT) {
                        // only one edge in band: factor = sigma(-m)
                        f = __builtin_amdgcn_rcpf(1.0f + __expf(m));
                    } else {
                        const float da = 1.0f + __expf(-xa);
                        const float db = 1.0f + __expf(-xb);
                        const float dc = 1.0f + __expf(-xc);
                        f = 1.0f - __builtin_amdgcn_rcpf(da * db * dc);
                    }
                    acc *= fmaxf(f, 1e-6f);
                }
                live = (acc > ACC_CUT_P);
            }
        }

        __syncthreads();   // B3: j-loop reads done before next chunk's writes
    }

    sAcc[t] = acc;
    __syncthreads();
    if (t < 64) {
        const float tot = sAcc[p] * sAcc[p + 64] * sAcc[p + 128] * sAcc[p + 192];
        out[(size_t)b * (IMG_S * IMG_S) + (size_t)gy * IMG_S + gx] = 1.0f - tot;
    }
}

extern "C" void kernel_launch(void* const* d_in, const int* in_sizes, int n_in,
                              void* d_out, int out_size, void* d_ws, size_t ws_size,
                              hipStream_t stream) {
    const float* verts = (const float*)d_in[0];
    const int* faces = (const int*)d_in[1];
    float* out = (float*)d_out;

    // ws layout: 3 arrays of float4[N_BATCH * FP]  (3 * 4*1600*16B = 307 KB)
    float4* gE0 = (float4*)d_ws;
    float4* gE1 = gE0 + (size_t)N_BATCH * FP;
    float4* gE2 = gE1 + (size_t)N_BATCH * FP;

    dim3 pgrid((N_FACES + 255) / 256, 1, N_BATCH);
    prep_faces<<<pgrid, 256, 0, stream>>>(verts, faces, gE0, gE1, gE2);

    dim3 grid(IMG_S / TILE, IMG_S / TILE, N_BATCH);
    silhouette_ws<<<grid, 256, 0, stream>>>(gE0, gE1, gE2, out);
}